// Round 1
// baseline (460.353 us; speedup 1.0000x reference)
//
#include <hip/hip_runtime.h>
#include <math.h>

#define D 2048
#define K 8
#define BLOCK 512          // 8 waves
#define ROWS_PER_ITER 8    // one row per wave

__device__ __forceinline__ float rcp_fast(float x) {
    return __builtin_amdgcn_rcpf(x);
}

// 0.5*y*(1+tanh(c*(y+0.044715*y^3))) == y * sigmoid(2c*(y + 0.044715*y^3))
__device__ __forceinline__ float gelu_tanh_fast(float y) {
    const float c2 = 1.5957691216057308f; // 2*sqrt(2/pi)
    float u = y * y;
    float w = y * fmaf(0.044715f, u, 1.0f);
    float e = __expf(-c2 * w);
    return y * rcp_fast(1.0f + e);
}

__global__ __launch_bounds__(BLOCK, 4)
void novelty_gelu_kernel(const float* __restrict__ x,
                         const float* __restrict__ P,
                         const float* __restrict__ plog_tau,
                         const float* __restrict__ plog_blend,
                         float* __restrict__ out,
                         int nrows)
{
    __shared__ float lds_p[K * D];     // 64 KiB
    __shared__ float s_invnp[K];

    const int tid = threadIdx.x;

    // ---- Stage prototypes into LDS (vectorized, coalesced) ----
    {
        const float4* src = (const float4*)P;
        float4* dst = (float4*)lds_p;
        #pragma unroll
        for (int i = 0; i < (K * D / 4) / BLOCK; ++i)   // 8 iters
            dst[i * BLOCK + tid] = src[i * BLOCK + tid];
    }
    __syncthreads();

    // ---- Per-k inverse norms: wave w handles prototype k=w ----
    {
        const int kk = tid >> 6;      // 0..7
        const int l  = tid & 63;
        float ssq = 0.f;
        #pragma unroll
        for (int j = 0; j < D / 64; ++j) {
            float v = lds_p[kk * D + l + j * 64];
            ssq = fmaf(v, v, ssq);
        }
        #pragma unroll
        for (int m = 32; m >= 1; m >>= 1)
            ssq += __shfl_xor(ssq, m);
        if (l == 0) s_invnp[kk] = 1.0f / fmaxf(sqrtf(ssq), 1e-8f);
    }
    __syncthreads();

    const float tau   = __expf(plog_tau[0]);
    const float alpha = 1.0f / (1.0f + __expf(-plog_blend[0]));

    const int wave = tid >> 6;   // 0..7
    const int lane = tid & 63;

    for (int row = blockIdx.x * ROWS_PER_ITER + wave; row < nrows;
         row += gridDim.x * ROWS_PER_ITER) {

        const float* xr = x + (size_t)row * D;

        // Whole row in registers: 8 x float4 per lane (coalesced 1 KiB/wave/load)
        float4 xs[8];
        #pragma unroll
        for (int j = 0; j < 8; ++j)
            xs[j] = *(const float4*)(xr + j * 256 + lane * 4);

        float ssq = 0.f;
        float dot[K];
        #pragma unroll
        for (int k = 0; k < K; ++k) dot[k] = 0.f;

        #pragma unroll
        for (int j = 0; j < 8; ++j) {
            float4 v = xs[j];
            ssq = fmaf(v.x, v.x, fmaf(v.y, v.y, fmaf(v.z, v.z, fmaf(v.w, v.w, ssq))));
            const int base = j * 256 + lane * 4;
            #pragma unroll
            for (int k = 0; k < K; ++k) {
                float4 p = *(const float4*)(lds_p + k * D + base);
                dot[k] = fmaf(v.x, p.x, fmaf(v.y, p.y, fmaf(v.z, p.z, fmaf(v.w, p.w, dot[k]))));
            }
        }

        // Butterfly-reduce 9 scalars across the wave
        #pragma unroll
        for (int m = 1; m < 64; m <<= 1) {
            ssq += __shfl_xor(ssq, m);
            #pragma unroll
            for (int k = 0; k < K; ++k)
                dot[k] += __shfl_xor(dot[k], m);
        }

        const float inv_nx = 1.0f / fmaxf(sqrtf(ssq), 1e-8f);
        float smax = -1.0f;
        #pragma unroll
        for (int k = 0; k < K; ++k) {
            float s = dot[k] * inv_nx * s_invnp[k];
            s = fminf(1.0f, fmaxf(-1.0f, s));
            smax = fmaxf(smax, s);
        }
        float md = fminf(fmaxf(1.0f - smax, 0.0f), 2.0f);
        const float novelty = 1.0f - __expf(-tau * md);
        float scale = 1.0f - alpha + alpha * novelty;
        scale = fminf(fmaxf(scale, 0.1f), 10.0f);

        // Epilogue straight from registers
        float* outr = out + (size_t)row * D;
        #pragma unroll
        for (int j = 0; j < 8; ++j) {
            float4 v = xs[j];
            float4 o;
            o.x = gelu_tanh_fast(v.x * scale);
            o.y = gelu_tanh_fast(v.y * scale);
            o.z = gelu_tanh_fast(v.z * scale);
            o.w = gelu_tanh_fast(v.w * scale);
            *(float4*)(outr + j * 256 + lane * 4) = o;
        }
    }
}

extern "C" void kernel_launch(void* const* d_in, const int* in_sizes, int n_in,
                              void* d_out, int out_size, void* d_ws, size_t ws_size,
                              hipStream_t stream) {
    const float* x  = (const float*)d_in[0];
    const float* P  = (const float*)d_in[1];
    const float* lt = (const float*)d_in[2];
    const float* lb = (const float*)d_in[3];
    float* out = (float*)d_out;

    const int nrows = in_sizes[0] / D;                 // 32768
    int grid = (nrows + ROWS_PER_ITER - 1) / ROWS_PER_ITER;
    if (grid > 1024) grid = 1024;                      // grid-stride; 2 blocks/CU resident

    novelty_gelu_kernel<<<grid, BLOCK, 0, stream>>>(x, P, lt, lb, out, nrows);
}

// Round 2
// 228.421 us; speedup vs baseline: 2.0154x; 2.0154x over previous
//
#include <hip/hip_runtime.h>
#include <math.h>

#define D 2048
#define K 8
#define BLOCK 256          // 4 waves
#define ROWS_PER_ITER 4    // one row per wave

__device__ __forceinline__ float rcp_fast(float x) {
    return __builtin_amdgcn_rcpf(x);
}

// 0.5*y*(1+tanh(c*(y+0.044715*y^3))) == y * sigmoid(2c*(y + 0.044715*y^3))
__device__ __forceinline__ float gelu_tanh_fast(float y) {
    const float c2 = 1.5957691216057308f; // 2*sqrt(2/pi)
    float u = y * y;
    float w = y * fmaf(0.044715f, u, 1.0f);
    float e = __expf(-c2 * w);
    return y * rcp_fast(1.0f + e);
}

__global__ __launch_bounds__(BLOCK, 2)
void novelty_gelu_kernel(const float* __restrict__ x,
                         const float* __restrict__ P,
                         const float* __restrict__ plog_tau,
                         const float* __restrict__ plog_blend,
                         float* __restrict__ out,
                         int nrows)
{
    __shared__ float lds_p[K * D];     // 64 KiB
    __shared__ float s_invnp[K];

    const int tid = threadIdx.x;

    // ---- Stage prototypes into LDS (vectorized, coalesced) ----
    {
        const float4* src = (const float4*)P;
        float4* dst = (float4*)lds_p;
        #pragma unroll
        for (int i = 0; i < (K * D / 4) / BLOCK; ++i)   // 16 iters
            dst[i * BLOCK + tid] = src[i * BLOCK + tid];
    }
    __syncthreads();

    // ---- Per-k inverse norms: 32-thread group per prototype ----
    {
        const int kk = tid >> 5;      // 0..7
        const int l  = tid & 31;
        float ssq = 0.f;
        #pragma unroll
        for (int j = 0; j < D / 32; ++j) {
            float v = lds_p[kk * D + l + j * 32];
            ssq = fmaf(v, v, ssq);
        }
        #pragma unroll
        for (int m = 16; m >= 1; m >>= 1)
            ssq += __shfl_xor(ssq, m);
        if (l == 0) s_invnp[kk] = 1.0f / fmaxf(sqrtf(ssq), 1e-8f);
    }
    __syncthreads();

    const float tau   = __expf(plog_tau[0]);
    const float alpha = 1.0f / (1.0f + __expf(-plog_blend[0]));

    const int wave = tid >> 6;   // 0..3
    const int lane = tid & 63;

    for (int row = blockIdx.x * ROWS_PER_ITER + wave; row < nrows;
         row += gridDim.x * ROWS_PER_ITER) {

        const float* xr = x + (size_t)row * D;

        // Whole row in registers: 8 x float4 per lane (coalesced 1 KiB/wave/load)
        float4 xs[8];
        #pragma unroll
        for (int j = 0; j < 8; ++j)
            xs[j] = *(const float4*)(xr + j * 256 + lane * 4);

        float ssq = 0.f;
        float dot[K];
        #pragma unroll
        for (int k = 0; k < K; ++k) dot[k] = 0.f;

        #pragma unroll
        for (int j = 0; j < 8; ++j) {
            float4 v = xs[j];
            ssq = fmaf(v.x, v.x, fmaf(v.y, v.y, fmaf(v.z, v.z, fmaf(v.w, v.w, ssq))));
            const int base = j * 256 + lane * 4;
            #pragma unroll
            for (int k = 0; k < K; ++k) {
                float4 p = *(const float4*)(lds_p + k * D + base);
                dot[k] = fmaf(v.x, p.x, fmaf(v.y, p.y, fmaf(v.z, p.z, fmaf(v.w, p.w, dot[k]))));
            }
        }

        // Butterfly-reduce 9 scalars across the wave
        #pragma unroll
        for (int m = 1; m < 64; m <<= 1) {
            ssq += __shfl_xor(ssq, m);
            #pragma unroll
            for (int k = 0; k < K; ++k)
                dot[k] += __shfl_xor(dot[k], m);
        }

        const float inv_nx = 1.0f / fmaxf(sqrtf(ssq), 1e-8f);
        float smax = -1.0f;
        #pragma unroll
        for (int k = 0; k < K; ++k) {
            float s = dot[k] * inv_nx * s_invnp[k];
            s = fminf(1.0f, fmaxf(-1.0f, s));
            smax = fmaxf(smax, s);
        }
        float md = fminf(fmaxf(1.0f - smax, 0.0f), 2.0f);
        const float novelty = 1.0f - __expf(-tau * md);
        float scale = 1.0f - alpha + alpha * novelty;
        scale = fminf(fmaxf(scale, 0.1f), 10.0f);

        // Epilogue straight from registers
        float* outr = out + (size_t)row * D;
        #pragma unroll
        for (int j = 0; j < 8; ++j) {
            float4 v = xs[j];
            float4 o;
            o.x = gelu_tanh_fast(v.x * scale);
            o.y = gelu_tanh_fast(v.y * scale);
            o.z = gelu_tanh_fast(v.z * scale);
            o.w = gelu_tanh_fast(v.w * scale);
            *(float4*)(outr + j * 256 + lane * 4) = o;
        }
    }
}

extern "C" void kernel_launch(void* const* d_in, const int* in_sizes, int n_in,
                              void* d_out, int out_size, void* d_ws, size_t ws_size,
                              hipStream_t stream) {
    const float* x  = (const float*)d_in[0];
    const float* P  = (const float*)d_in[1];
    const float* lt = (const float*)d_in[2];
    const float* lb = (const float*)d_in[3];
    float* out = (float*)d_out;

    const int nrows = in_sizes[0] / D;                 // 32768
    int grid = (nrows + ROWS_PER_ITER - 1) / ROWS_PER_ITER;
    if (grid > 2048) grid = 2048;                      // grid-stride

    novelty_gelu_kernel<<<grid, BLOCK, 0, stream>>>(x, P, lt, lb, out, nrows);
}

// Round 3
// 146.079 us; speedup vs baseline: 3.1514x; 1.5637x over previous
//
#include <hip/hip_runtime.h>
#include <math.h>

#define D 2048
#define K 8
#define BLOCK 256   // 4 waves; one row per block, thread owns 8 contiguous cols

__device__ __forceinline__ float rcp_fast(float x) {
    return __builtin_amdgcn_rcpf(x);
}

// 0.5*y*(1+tanh(c*(y+0.044715*y^3))) == y * sigmoid(2c*(y + 0.044715*y^3))
__device__ __forceinline__ float gelu_tanh_fast(float y) {
    const float c2 = 1.5957691216057308f; // 2*sqrt(2/pi)
    float u = y * y;
    float w = y * fmaf(0.044715f, u, 1.0f);
    return y * rcp_fast(1.0f + __expf(-c2 * w));
}

__device__ __forceinline__ float dot8(const float4& a0, const float4& a1,
                                      const float4& b0, const float4& b1) {
    float s;
    s = a0.x * b0.x;
    s = fmaf(a0.y, b0.y, s);
    s = fmaf(a0.z, b0.z, s);
    s = fmaf(a0.w, b0.w, s);
    s = fmaf(a1.x, b1.x, s);
    s = fmaf(a1.y, b1.y, s);
    s = fmaf(a1.z, b1.z, s);
    s = fmaf(a1.w, b1.w, s);
    return s;
}

__global__ __launch_bounds__(BLOCK, 2)
void novelty_gelu_kernel(const float* __restrict__ x,
                         const float* __restrict__ P,
                         const float* __restrict__ plog_tau,
                         const float* __restrict__ plog_blend,
                         float* __restrict__ out,
                         int nrows)
{
    __shared__ float red[2][4][12];   // [buf][wave][ssq + 8 dots], padded

    const int tid  = threadIdx.x;
    const int wave = tid >> 6;
    const int lane = tid & 63;
    const int col  = tid * 8;         // this thread's 8 columns of the row

    // ---- P fragments into registers, then pre-scale by 1/||P_k|| ----
    float4 pf[K][2];
    #pragma unroll
    for (int k = 0; k < K; ++k) {
        pf[k][0] = *(const float4*)(P + k * D + col);
        pf[k][1] = *(const float4*)(P + k * D + col + 4);
    }
    {
        float nk[K];
        #pragma unroll
        for (int k = 0; k < K; ++k)
            nk[k] = dot8(pf[k][0], pf[k][1], pf[k][0], pf[k][1]);
        #pragma unroll
        for (int m = 1; m < 64; m <<= 1) {
            #pragma unroll
            for (int k = 0; k < K; ++k)
                nk[k] += __shfl_xor(nk[k], m);
        }
        if (lane == 0) {
            #pragma unroll
            for (int k = 0; k < K; ++k) red[0][wave][k] = nk[k];
        }
        __syncthreads();
        #pragma unroll
        for (int k = 0; k < K; ++k) {
            float s = red[0][0][k] + red[0][1][k] + red[0][2][k] + red[0][3][k];
            float inv = 1.0f / fmaxf(sqrtf(s), 1e-8f);
            pf[k][0].x *= inv; pf[k][0].y *= inv; pf[k][0].z *= inv; pf[k][0].w *= inv;
            pf[k][1].x *= inv; pf[k][1].y *= inv; pf[k][1].z *= inv; pf[k][1].w *= inv;
        }
        __syncthreads();   // red[0] reused by first row iteration
    }

    const float tau   = __expf(plog_tau[0]);
    const float alpha = 1.0f / (1.0f + __expf(-plog_blend[0]));
    const float oma   = 1.0f - alpha;

    const int stride = gridDim.x;
    int row = blockIdx.x;
    int buf = 0;

    // prefetch first row
    float4 a0, a1;
    if (row < nrows) {
        const float* xr = x + (size_t)row * D + col;
        a0 = *(const float4*)(xr);
        a1 = *(const float4*)(xr + 4);
    }

    while (row < nrows) {
        const int nrow = row + stride;
        float4 b0, b1;
        if (nrow < nrows) {                 // prefetch next row early
            const float* xn = x + (size_t)nrow * D + col;
            b0 = *(const float4*)(xn);
            b1 = *(const float4*)(xn + 4);
        }

        // per-thread partials: ssq + 8 dots (P pre-normalized)
        float ssq = dot8(a0, a1, a0, a1);
        float dot[K];
        #pragma unroll
        for (int k = 0; k < K; ++k)
            dot[k] = dot8(a0, a1, pf[k][0], pf[k][1]);

        // intra-wave butterfly reduce (9 values)
        #pragma unroll
        for (int m = 1; m < 64; m <<= 1) {
            ssq += __shfl_xor(ssq, m);
            #pragma unroll
            for (int k = 0; k < K; ++k)
                dot[k] += __shfl_xor(dot[k], m);
        }

        // cross-wave via LDS (double-buffered -> single barrier per row)
        if (lane == 0) {
            red[buf][wave][0] = ssq;
            #pragma unroll
            for (int k = 0; k < K; ++k) red[buf][wave][1 + k] = dot[k];
        }
        __syncthreads();

        float tssq = red[buf][0][0] + red[buf][1][0] + red[buf][2][0] + red[buf][3][0];
        float dmax = -3.0e38f;
        #pragma unroll
        for (int k = 0; k < K; ++k) {
            float t = red[buf][0][1 + k] + red[buf][1][1 + k]
                    + red[buf][2][1 + k] + red[buf][3][1 + k];
            dmax = fmaxf(dmax, t);
        }
        const float inv_nx = 1.0f / fmaxf(sqrtf(tssq), 1e-8f);
        float s  = fminf(1.0f, fmaxf(-1.0f, dmax * inv_nx));
        float md = fminf(fmaxf(1.0f - s, 0.0f), 2.0f);
        float scale = oma + alpha * (1.0f - __expf(-tau * md));
        scale = fminf(fmaxf(scale, 0.1f), 10.0f);

        // epilogue from registers
        float* outr = out + (size_t)row * D + col;
        float4 o0, o1;
        o0.x = gelu_tanh_fast(a0.x * scale);
        o0.y = gelu_tanh_fast(a0.y * scale);
        o0.z = gelu_tanh_fast(a0.z * scale);
        o0.w = gelu_tanh_fast(a0.w * scale);
        o1.x = gelu_tanh_fast(a1.x * scale);
        o1.y = gelu_tanh_fast(a1.y * scale);
        o1.z = gelu_tanh_fast(a1.z * scale);
        o1.w = gelu_tanh_fast(a1.w * scale);
        *(float4*)(outr)     = o0;
        *(float4*)(outr + 4) = o1;

        a0 = b0; a1 = b1;
        row = nrow;
        buf ^= 1;
    }
}

extern "C" void kernel_launch(void* const* d_in, const int* in_sizes, int n_in,
                              void* d_out, int out_size, void* d_ws, size_t ws_size,
                              hipStream_t stream) {
    const float* x  = (const float*)d_in[0];
    const float* P  = (const float*)d_in[1];
    const float* lt = (const float*)d_in[2];
    const float* lb = (const float*)d_in[3];
    float* out = (float*)d_out;

    const int nrows = in_sizes[0] / D;   // 32768
    int grid = nrows < 2048 ? nrows : 2048;

    novelty_gelu_kernel<<<grid, BLOCK, 0, stream>>>(x, P, lt, lb, out, nrows);
}